// Round 3
// baseline (189.379 us; speedup 1.0000x reference)
//
#include <hip/hip_runtime.h>
#include <math.h>

#define NG    2048
#define IMG_W 128
#define IMG_H 128
#define NPIX  (IMG_W * IMG_H)
#define NSEG  16
#define SEG   (NG / NSEG)      // 128
#define GSTRIDE 12             // floats per record (9 used + 3 pad, 48B)
#define F_FX  100.0f
#define F_FY  100.0f
#define NEARZ 1.1f
#define EPS_C 1e-6f
#define LIMU  (IMG_W / (2.0f * F_FX))
#define LIMV  (IMG_H / (2.0f * F_FY))
#define LOG2E 1.4426950408889634f

// ws layout (floats):
//   [0, NG*GSTRIDE)                    : depth-sorted records (AoS, prescaled conic)
//   [OFF_PART, OFF_PART + 4*NSEG*NPIX) : segment partials (cr,cg,cb,T planes)
//   [OFF_CNT, OFF_CNT + 64)            : per-tile completion counters (int)
#define OFF_PART (NG * GSTRIDE)
#define OFF_CNT  (OFF_PART + 4 * NSEG * NPIX)

__device__ __forceinline__ void quat_to_rot(float w, float x, float y, float z,
                                            float R[9]) {
    float n = sqrtf(w * w + x * x + y * y + z * z) + 1e-12f;
    w /= n; x /= n; y /= n; z /= n;
    R[0] = 1.0f - 2.0f * (y * y + z * z);
    R[1] = 2.0f * (x * y - w * z);
    R[2] = 2.0f * (x * z + w * y);
    R[3] = 2.0f * (x * y + w * z);
    R[4] = 1.0f - 2.0f * (x * x + z * z);
    R[5] = 2.0f * (y * z - w * x);
    R[6] = 2.0f * (x * z - w * y);
    R[7] = 2.0f * (y * z + w * x);
    R[8] = 1.0f - 2.0f * (x * x + y * y);
}

// 8 blocks x 256 threads: stage pos in LDS, compute all 2048 depth keys
// (redundant per block, deterministic -> globally consistent), each thread
// builds one gaussian's record, rank-sorts via LDS count, scatters to slot.
__global__ __launch_bounds__(256) void prep_rank_kernel(
    const float* __restrict__ pos, const float* __restrict__ rgb,
    const float* __restrict__ opa, const float* __restrict__ quat,
    const float* __restrict__ scale, const float* __restrict__ wq,
    const float* __restrict__ wt, float* __restrict__ rec,
    int* __restrict__ cnt) {
    __shared__ float spos[NG * 3];                         // 24 KB
    __shared__ __align__(16) unsigned long long skey[NG];  // 16 KB
    const int tid = threadIdx.x;

    if (blockIdx.x == 0 && tid < 64) cnt[tid] = 0;  // gate counters for render

#pragma unroll
    for (int k = 0; k < (NG * 3 / 4) / 256; ++k)
        ((float4*)spos)[tid + k * 256] = ((const float4*)pos)[tid + k * 256];

    float cm[9];
    quat_to_rot(wq[0], wq[1], wq[2], wq[3], cm);
    const float t0 = wt[0], t1 = wt[1], t2 = wt[2];
    __syncthreads();

#pragma unroll
    for (int k = 0; k < NG / 256; ++k) {
        const int j = tid + k * 256;
        const float px = spos[3 * j], py = spos[3 * j + 1], pz = spos[3 * j + 2];
        const float x = cm[0] * px + cm[1] * py + cm[2] * pz + t0;
        const float y = cm[3] * px + cm[4] * py + cm[5] * pz + t1;
        const float z = cm[6] * px + cm[7] * py + cm[8] * pz + t2;
        const float dn = sqrtf(x * x + y * y + z * z);
        bool m = z > NEARZ;
        const float zs = m ? z : 1.0f;
        m = m && (fabsf(x / zs) < LIMU) && (fabsf(y / zs) < LIMV);
        const float depth = m ? dn : __int_as_float(0x7f800000);
        skey[j] = (((unsigned long long)__float_as_uint(depth)) << 32) |
                  (unsigned long long)(unsigned)j;
    }
    __syncthreads();

    const int i = blockIdx.x * 256 + tid;
    const float px = spos[3 * i], py = spos[3 * i + 1], pz = spos[3 * i + 2];
    const float x = cm[0] * px + cm[1] * py + cm[2] * pz + t0;
    const float y = cm[3] * px + cm[4] * py + cm[5] * pz + t1;
    const float z = cm[6] * px + cm[7] * py + cm[8] * pz + t2;
    bool m = z > NEARZ;
    const float zs = m ? z : 1.0f;
    const float u = x / zs;
    const float v = y / zs;
    m = m && (fabsf(u) < LIMU) && (fabsf(v) < LIMV);
    const float iz = 1.0f / zs;
    const float iz2 = iz * iz;

    float Rg[9];
    quat_to_rot(quat[4 * i], quat[4 * i + 1], quat[4 * i + 2], quat[4 * i + 3],
                Rg);
    const float s0 = scale[3 * i], s1 = scale[3 * i + 1], s2 = scale[3 * i + 2];
    const float RS0 = Rg[0] * s0, RS1 = Rg[1] * s1, RS2 = Rg[2] * s2;
    const float RS3 = Rg[3] * s0, RS4 = Rg[4] * s1, RS5 = Rg[5] * s2;
    const float RS6 = Rg[6] * s0, RS7 = Rg[7] * s1, RS8 = Rg[8] * s2;

    const float xiz2 = x * iz2, yiz2 = y * iz2;
    const float w00 = iz * cm[0] - xiz2 * cm[6];
    const float w01 = iz * cm[1] - xiz2 * cm[7];
    const float w02 = iz * cm[2] - xiz2 * cm[8];
    const float w10 = iz * cm[3] - yiz2 * cm[6];
    const float w11 = iz * cm[4] - yiz2 * cm[7];
    const float w12 = iz * cm[5] - yiz2 * cm[8];

    const float e00 = w00 * RS0 + w01 * RS3 + w02 * RS6;
    const float e01 = w00 * RS1 + w01 * RS4 + w02 * RS7;
    const float e02 = w00 * RS2 + w01 * RS5 + w02 * RS8;
    const float e10 = w10 * RS0 + w11 * RS3 + w12 * RS6;
    const float e11 = w10 * RS1 + w11 * RS4 + w12 * RS7;
    const float e12 = w10 * RS2 + w11 * RS5 + w12 * RS8;

    const float a = e00 * e00 + e01 * e01 + e02 * e02 + EPS_C;
    const float b = e00 * e10 + e01 * e11 + e02 * e12;
    const float c = e10 * e10 + e11 * e11 + e12 * e12 + EPS_C;
    const float invdet = 1.0f / fmaxf(a * c - b * b, 1e-12f);
    // prescale: pw2 = A2*dx^2 + C2*dy^2 + B2*dx*dy is log2-domain power
    const float A2 = -0.5f * LOG2E * (c * invdet);
    const float C2 = -0.5f * LOG2E * (a * invdet);
    const float B2 = LOG2E * (b * invdet);

    // rank = # keys < mine (keys unique -> exact stable argsort), 2 keys/b128
    const unsigned long long myk = skey[i];
    const ulonglong2* sk2 = (const ulonglong2*)skey;
    int rank = 0;
#pragma unroll 8
    for (int j2 = 0; j2 < NG / 2; ++j2) {
        const ulonglong2 kk = sk2[j2];
        rank += (kk.x < myk) ? 1 : 0;
        rank += (kk.y < myk) ? 1 : 0;
    }

    float4* dst = (float4*)(rec + rank * GSTRIDE);
    dst[0] = make_float4(u, v, A2, B2);
    dst[1] = make_float4(C2, m ? opa[i] : 0.0f, rgb[3 * i], rgb[3 * i + 1]);
    dst[2] = make_float4(rgb[3 * i + 2], 0.0f, 0.0f, 0.0f);
}

// grid (64 pixel-strips, NSEG segments), 256 threads = 1 pixel/thread.
// Each block composites its 128-gaussian segment for 256 pixels, writes the
// per-segment partial; the LAST block to finish a strip (fence+atomic gate)
// combines all NSEG partials in depth order and writes the image.
__global__ __launch_bounds__(256) void render_fused_kernel(
    const float* __restrict__ rec, float* __restrict__ part,
    int* __restrict__ cnt, float* __restrict__ out) {
    __shared__ float gsh[SEG * GSTRIDE];  // 6 KB
    __shared__ int sflag;

    const int t = threadIdx.x;
    const int seg = blockIdx.y;
    const float* gsrc = rec + seg * SEG * GSTRIDE;

    for (int i4 = t; i4 < (SEG * GSTRIDE) / 4; i4 += 256)
        ((float4*)gsh)[i4] = ((const float4*)gsrc)[i4];
    __syncthreads();

    const int p = blockIdx.x * 256 + t;
    const int ix = p & (IMG_W - 1);
    const int iy = p >> 7;
    const float pu = (ix + 0.5f - IMG_W * 0.5f) / F_FX;
    const float pv = (iy + 0.5f - IMG_H * 0.5f) / F_FY;

    float T = 1.0f, cr = 0.0f, cg = 0.0f, cb = 0.0f;
#pragma unroll 4
    for (int j = 0; j < SEG; ++j) {
        const float4 q0 = ((const float4*)gsh)[j * 3];      // u v A2 B2
        const float4 q1 = ((const float4*)gsh)[j * 3 + 1];  // C2 o r g
        const float qb = gsh[j * GSTRIDE + 8];              // b
        const float dx = pu - q0.x;
        const float dy = pv - q0.y;
        const float pwa = fmaf(q0.z, dx, q0.w * dy);   // A2*dx + B2*dy
        const float pwc = q1.x * dy;                   // C2*dy
        float pw = fmaf(dx, pwa, pwc * dy);            // log2-domain power
        pw = fminf(pw, 0.0f);
        const float al = fminf(q1.y * __builtin_amdgcn_exp2f(pw), 0.99f);
        const float wgt = T * al;
        cr = fmaf(wgt, q1.z, cr);
        cg = fmaf(wgt, q1.w, cg);
        cb = fmaf(wgt, qb, cb);
        T -= wgt;  // == T*(1-al) exactly re-associated
    }

    const int o = seg * NPIX + p;
    part[o] = cr;
    part[NSEG * NPIX + o] = cg;
    part[2 * NSEG * NPIX + o] = cb;
    part[3 * NSEG * NPIX + o] = T;

    // last-block-per-strip combine gate
    __threadfence();
    if (t == 0) {
        const int old = atomicAdd(&cnt[blockIdx.x], 1);
        sflag = (old == NSEG - 1) ? 1 : 0;
    }
    __syncthreads();
    if (sflag) {
        __threadfence();  // acquire: others' partials now visible
        float Tc = 1.0f, fr = 0.0f, fg = 0.0f, fb = 0.0f;
#pragma unroll
        for (int s = 0; s < NSEG; ++s) {
            const int q = s * NPIX + p;
            fr = fmaf(Tc, part[q], fr);
            fg = fmaf(Tc, part[NSEG * NPIX + q], fg);
            fb = fmaf(Tc, part[2 * NSEG * NPIX + q], fb);
            Tc *= part[3 * NSEG * NPIX + q];
        }
        out[3 * p + 0] = fr;
        out[3 * p + 1] = fg;
        out[3 * p + 2] = fb;
    }
}

extern "C" void kernel_launch(void* const* d_in, const int* in_sizes, int n_in,
                              void* d_out, int out_size, void* d_ws,
                              size_t ws_size, hipStream_t stream) {
    const float* pos   = (const float*)d_in[0];
    const float* rgb   = (const float*)d_in[1];
    const float* opa   = (const float*)d_in[2];
    const float* quat  = (const float*)d_in[3];
    const float* scale = (const float*)d_in[4];
    const float* wq    = (const float*)d_in[5];
    const float* wt    = (const float*)d_in[6];
    float* rec  = (float*)d_ws;
    float* part = rec + OFF_PART;
    int*   cnt  = (int*)(rec + OFF_CNT);
    float* out  = (float*)d_out;

    prep_rank_kernel<<<NG / 256, 256, 0, stream>>>(pos, rgb, opa, quat, scale,
                                                   wq, wt, rec, cnt);
    render_fused_kernel<<<dim3(NPIX / 256, NSEG), 256, 0, stream>>>(rec, part,
                                                                    cnt, out);
}

// Round 4
// 108.045 us; speedup vs baseline: 1.7528x; 1.7528x over previous
//
#include <hip/hip_runtime.h>
#include <math.h>

#define NG    2048
#define IMG_W 128
#define IMG_H 128
#define NPIX  (IMG_W * IMG_H)
#define NSEG  16
#define SEG   (NG / NSEG)      // 128
#define GSTRIDE 12             // floats per record (9 used + 3 pad, 48B)
#define F_FX  100.0f
#define F_FY  100.0f
#define NEARZ 1.1f
#define EPS_C 1e-6f
#define LIMU  (IMG_W / (2.0f * F_FX))
#define LIMV  (IMG_H / (2.0f * F_FY))
#define LOG2E 1.4426950408889634f

// ws layout (floats):
//   [0, NG*GSTRIDE)                    : depth-sorted records (AoS, prescaled conic)
//   [OFF_PART, OFF_PART + 4*NSEG*NPIX) : segment partials (cr,cg,cb,T planes)
// NOTE: no cross-block fences anywhere — R3 showed device-scope __threadfence
// on gfx950 (non-coherent per-XCD L2) costs ~90us across 1024 blocks. A
// separate 2us combine dispatch is strictly better.
#define OFF_PART (NG * GSTRIDE)

__device__ __forceinline__ void quat_to_rot(float w, float x, float y, float z,
                                            float R[9]) {
    float n = sqrtf(w * w + x * x + y * y + z * z) + 1e-12f;
    w /= n; x /= n; y /= n; z /= n;
    R[0] = 1.0f - 2.0f * (y * y + z * z);
    R[1] = 2.0f * (x * y - w * z);
    R[2] = 2.0f * (x * z + w * y);
    R[3] = 2.0f * (x * y + w * z);
    R[4] = 1.0f - 2.0f * (x * x + z * z);
    R[5] = 2.0f * (y * z - w * x);
    R[6] = 2.0f * (x * z - w * y);
    R[7] = 2.0f * (y * z + w * x);
    R[8] = 1.0f - 2.0f * (x * x + y * y);
}

// 8 blocks x 256 threads: stage pos in LDS, compute all 2048 depth keys
// (redundant per block, deterministic -> globally consistent), each thread
// builds one gaussian's record, rank-sorts via LDS count, scatters to slot.
__global__ __launch_bounds__(256) void prep_rank_kernel(
    const float* __restrict__ pos, const float* __restrict__ rgb,
    const float* __restrict__ opa, const float* __restrict__ quat,
    const float* __restrict__ scale, const float* __restrict__ wq,
    const float* __restrict__ wt, float* __restrict__ rec) {
    __shared__ float spos[NG * 3];                         // 24 KB
    __shared__ __align__(16) unsigned long long skey[NG];  // 16 KB
    const int tid = threadIdx.x;

#pragma unroll
    for (int k = 0; k < (NG * 3 / 4) / 256; ++k)
        ((float4*)spos)[tid + k * 256] = ((const float4*)pos)[tid + k * 256];

    float cm[9];
    quat_to_rot(wq[0], wq[1], wq[2], wq[3], cm);
    const float t0 = wt[0], t1 = wt[1], t2 = wt[2];
    __syncthreads();

#pragma unroll
    for (int k = 0; k < NG / 256; ++k) {
        const int j = tid + k * 256;
        const float px = spos[3 * j], py = spos[3 * j + 1], pz = spos[3 * j + 2];
        const float x = cm[0] * px + cm[1] * py + cm[2] * pz + t0;
        const float y = cm[3] * px + cm[4] * py + cm[5] * pz + t1;
        const float z = cm[6] * px + cm[7] * py + cm[8] * pz + t2;
        const float dn = sqrtf(x * x + y * y + z * z);
        bool m = z > NEARZ;
        const float zs = m ? z : 1.0f;
        m = m && (fabsf(x / zs) < LIMU) && (fabsf(y / zs) < LIMV);
        const float depth = m ? dn : __int_as_float(0x7f800000);
        skey[j] = (((unsigned long long)__float_as_uint(depth)) << 32) |
                  (unsigned long long)(unsigned)j;
    }
    __syncthreads();

    const int i = blockIdx.x * 256 + tid;
    const float px = spos[3 * i], py = spos[3 * i + 1], pz = spos[3 * i + 2];
    const float x = cm[0] * px + cm[1] * py + cm[2] * pz + t0;
    const float y = cm[3] * px + cm[4] * py + cm[5] * pz + t1;
    const float z = cm[6] * px + cm[7] * py + cm[8] * pz + t2;
    bool m = z > NEARZ;
    const float zs = m ? z : 1.0f;
    const float u = x / zs;
    const float v = y / zs;
    m = m && (fabsf(u) < LIMU) && (fabsf(v) < LIMV);
    const float iz = 1.0f / zs;
    const float iz2 = iz * iz;

    float Rg[9];
    quat_to_rot(quat[4 * i], quat[4 * i + 1], quat[4 * i + 2], quat[4 * i + 3],
                Rg);
    const float s0 = scale[3 * i], s1 = scale[3 * i + 1], s2 = scale[3 * i + 2];
    const float RS0 = Rg[0] * s0, RS1 = Rg[1] * s1, RS2 = Rg[2] * s2;
    const float RS3 = Rg[3] * s0, RS4 = Rg[4] * s1, RS5 = Rg[5] * s2;
    const float RS6 = Rg[6] * s0, RS7 = Rg[7] * s1, RS8 = Rg[8] * s2;

    const float xiz2 = x * iz2, yiz2 = y * iz2;
    const float w00 = iz * cm[0] - xiz2 * cm[6];
    const float w01 = iz * cm[1] - xiz2 * cm[7];
    const float w02 = iz * cm[2] - xiz2 * cm[8];
    const float w10 = iz * cm[3] - yiz2 * cm[6];
    const float w11 = iz * cm[4] - yiz2 * cm[7];
    const float w12 = iz * cm[5] - yiz2 * cm[8];

    const float e00 = w00 * RS0 + w01 * RS3 + w02 * RS6;
    const float e01 = w00 * RS1 + w01 * RS4 + w02 * RS7;
    const float e02 = w00 * RS2 + w01 * RS5 + w02 * RS8;
    const float e10 = w10 * RS0 + w11 * RS3 + w12 * RS6;
    const float e11 = w10 * RS1 + w11 * RS4 + w12 * RS7;
    const float e12 = w10 * RS2 + w11 * RS5 + w12 * RS8;

    const float a = e00 * e00 + e01 * e01 + e02 * e02 + EPS_C;
    const float b = e00 * e10 + e01 * e11 + e02 * e12;
    const float c = e10 * e10 + e11 * e11 + e12 * e12 + EPS_C;
    const float invdet = 1.0f / fmaxf(a * c - b * b, 1e-12f);
    // prescale: pw = A2*dx^2 + C2*dy^2 + B2*dx*dy in log2 domain
    const float A2 = -0.5f * LOG2E * (c * invdet);
    const float C2 = -0.5f * LOG2E * (a * invdet);
    const float B2 = LOG2E * (b * invdet);

    // rank = # keys < mine (keys unique -> exact stable argsort), 2 keys/b128
    const unsigned long long myk = skey[i];
    const ulonglong2* sk2 = (const ulonglong2*)skey;
    int rank = 0;
#pragma unroll 8
    for (int j2 = 0; j2 < NG / 2; ++j2) {
        const ulonglong2 kk = sk2[j2];
        rank += (kk.x < myk) ? 1 : 0;
        rank += (kk.y < myk) ? 1 : 0;
    }

    float4* dst = (float4*)(rec + rank * GSTRIDE);
    dst[0] = make_float4(u, v, A2, B2);
    dst[1] = make_float4(C2, m ? opa[i] : 0.0f, rgb[3 * i], rgb[3 * i + 1]);
    dst[2] = make_float4(rgb[3 * i + 2], 0.0f, 0.0f, 0.0f);
}

// grid (64 pixel-strips, NSEG segments), 256 threads = 1 pixel/thread.
// Each block composites its 128-gaussian segment for 256 pixels and writes
// the per-segment partial (premultiplied rgb, transmittance). No fences.
__global__ __launch_bounds__(256) void render_kernel(
    const float* __restrict__ rec, float* __restrict__ part) {
    __shared__ float gsh[SEG * GSTRIDE];  // 6 KB

    const int t = threadIdx.x;
    const int seg = blockIdx.y;
    const float* gsrc = rec + seg * SEG * GSTRIDE;

    for (int i4 = t; i4 < (SEG * GSTRIDE) / 4; i4 += 256)
        ((float4*)gsh)[i4] = ((const float4*)gsrc)[i4];
    __syncthreads();

    const int p = blockIdx.x * 256 + t;
    const int ix = p & (IMG_W - 1);
    const int iy = p >> 7;
    const float pu = (ix + 0.5f - IMG_W * 0.5f) / F_FX;
    const float pv = (iy + 0.5f - IMG_H * 0.5f) / F_FY;

    float T = 1.0f, cr = 0.0f, cg = 0.0f, cb = 0.0f;
#pragma unroll 4
    for (int j = 0; j < SEG; ++j) {
        const float4 q0 = ((const float4*)gsh)[j * 3];      // u v A2 B2
        const float4 q1 = ((const float4*)gsh)[j * 3 + 1];  // C2 o r g
        const float qb = gsh[j * GSTRIDE + 8];              // b
        const float dx = pu - q0.x;
        const float dy = pv - q0.y;
        const float pwa = fmaf(q0.z, dx, q0.w * dy);   // A2*dx + B2*dy
        const float pwc = q1.x * dy;                   // C2*dy
        float pw = fmaf(dx, pwa, pwc * dy);            // log2-domain power
        pw = fminf(pw, 0.0f);
        const float al = fminf(q1.y * __builtin_amdgcn_exp2f(pw), 0.99f);
        const float wgt = T * al;
        cr = fmaf(wgt, q1.z, cr);
        cg = fmaf(wgt, q1.w, cg);
        cb = fmaf(wgt, qb, cb);
        T -= wgt;  // == T*(1-al) exactly
    }

    const int o = seg * NPIX + p;
    part[o] = cr;
    part[NSEG * NPIX + o] = cg;
    part[2 * NSEG * NPIX + o] = cb;
    part[3 * NSEG * NPIX + o] = T;
}

// Combine segment partials in depth order (over-operator associativity).
__global__ __launch_bounds__(256) void combine_kernel(
    const float* __restrict__ part, float* __restrict__ out) {
    const int p = blockIdx.x * 256 + threadIdx.x;
    float T = 1.0f, cr = 0.0f, cg = 0.0f, cb = 0.0f;
#pragma unroll
    for (int s = 0; s < NSEG; ++s) {
        const int o = s * NPIX + p;
        cr = fmaf(T, part[o], cr);
        cg = fmaf(T, part[NSEG * NPIX + o], cg);
        cb = fmaf(T, part[2 * NSEG * NPIX + o], cb);
        T *= part[3 * NSEG * NPIX + o];
    }
    out[3 * p + 0] = cr;
    out[3 * p + 1] = cg;
    out[3 * p + 2] = cb;
}

extern "C" void kernel_launch(void* const* d_in, const int* in_sizes, int n_in,
                              void* d_out, int out_size, void* d_ws,
                              size_t ws_size, hipStream_t stream) {
    const float* pos   = (const float*)d_in[0];
    const float* rgb   = (const float*)d_in[1];
    const float* opa   = (const float*)d_in[2];
    const float* quat  = (const float*)d_in[3];
    const float* scale = (const float*)d_in[4];
    const float* wq    = (const float*)d_in[5];
    const float* wt    = (const float*)d_in[6];
    float* rec  = (float*)d_ws;
    float* part = rec + OFF_PART;
    float* out  = (float*)d_out;

    prep_rank_kernel<<<NG / 256, 256, 0, stream>>>(pos, rgb, opa, quat, scale,
                                                   wq, wt, rec);
    render_kernel<<<dim3(NPIX / 256, NSEG), 256, 0, stream>>>(rec, part);
    combine_kernel<<<NPIX / 256, 256, 0, stream>>>(part, out);
}

// Round 5
// 106.941 us; speedup vs baseline: 1.7709x; 1.0103x over previous
//
#include <hip/hip_runtime.h>
#include <math.h>

#define NG    2048
#define IMG_W 128
#define IMG_H 128
#define NPIX  (IMG_W * IMG_H)
#define GSTRIDE 12             // floats per record: u v A2 B2 | C2 o r g | b dxm dym pad
#define F_FX  100.0f
#define F_FY  100.0f
#define NEARZ 1.1f
#define EPS_C 1e-6f
#define LIMU  (IMG_W / (2.0f * F_FX))
#define LIMV  (IMG_H / (2.0f * F_FY))
#define LOG2E 1.4426950408889634f
#define L2CUT 30.0f            // log2-domain alpha cutoff: excluded pairs have
                               // alpha < opa*2^-30 ~ 1e-9 -> color err <= 2e-6
#define TILE  16               // 16x16 px tiles, 8x8 = 64 tiles
#define CHUNK 256              // composite staging chunk (records)

// ws layout (floats): [0, NG*GSTRIDE) depth-sorted records. Nothing else.
// NOTE (R3 lesson): never use device-scope fences cross-block on gfx950 —
// ~90us over 1024 blocks. Kernel boundaries are the only cheap global sync.

__device__ __forceinline__ void quat_to_rot(float w, float x, float y, float z,
                                            float R[9]) {
    float n = sqrtf(w * w + x * x + y * y + z * z) + 1e-12f;
    w /= n; x /= n; y /= n; z /= n;
    R[0] = 1.0f - 2.0f * (y * y + z * z);
    R[1] = 2.0f * (x * y - w * z);
    R[2] = 2.0f * (x * z + w * y);
    R[3] = 2.0f * (x * y + w * z);
    R[4] = 1.0f - 2.0f * (x * x + z * z);
    R[5] = 2.0f * (y * z - w * x);
    R[6] = 2.0f * (x * z - w * y);
    R[7] = 2.0f * (y * z + w * x);
    R[8] = 1.0f - 2.0f * (x * x + y * y);
}

// 8 blocks x 256 threads: stage pos in LDS, compute all 2048 depth keys
// (redundant per block, deterministic -> globally consistent), each thread
// builds one gaussian's record (+conservative bbox extents), rank-sorts via
// LDS count, scatters to its sorted slot.
__global__ __launch_bounds__(256) void prep_rank_kernel(
    const float* __restrict__ pos, const float* __restrict__ rgb,
    const float* __restrict__ opa, const float* __restrict__ quat,
    const float* __restrict__ scale, const float* __restrict__ wq,
    const float* __restrict__ wt, float* __restrict__ rec) {
    __shared__ float spos[NG * 3];                         // 24 KB
    __shared__ __align__(16) unsigned long long skey[NG];  // 16 KB
    const int tid = threadIdx.x;

#pragma unroll
    for (int k = 0; k < (NG * 3 / 4) / 256; ++k)
        ((float4*)spos)[tid + k * 256] = ((const float4*)pos)[tid + k * 256];

    float cm[9];
    quat_to_rot(wq[0], wq[1], wq[2], wq[3], cm);
    const float t0 = wt[0], t1 = wt[1], t2 = wt[2];
    __syncthreads();

#pragma unroll
    for (int k = 0; k < NG / 256; ++k) {
        const int j = tid + k * 256;
        const float px = spos[3 * j], py = spos[3 * j + 1], pz = spos[3 * j + 2];
        const float x = cm[0] * px + cm[1] * py + cm[2] * pz + t0;
        const float y = cm[3] * px + cm[4] * py + cm[5] * pz + t1;
        const float z = cm[6] * px + cm[7] * py + cm[8] * pz + t2;
        const float dn = sqrtf(x * x + y * y + z * z);
        bool m = z > NEARZ;
        const float zs = m ? z : 1.0f;
        m = m && (fabsf(x / zs) < LIMU) && (fabsf(y / zs) < LIMV);
        const float depth = m ? dn : __int_as_float(0x7f800000);
        skey[j] = (((unsigned long long)__float_as_uint(depth)) << 32) |
                  (unsigned long long)(unsigned)j;
    }
    __syncthreads();

    const int i = blockIdx.x * 256 + tid;
    const float px = spos[3 * i], py = spos[3 * i + 1], pz = spos[3 * i + 2];
    const float x = cm[0] * px + cm[1] * py + cm[2] * pz + t0;
    const float y = cm[3] * px + cm[4] * py + cm[5] * pz + t1;
    const float z = cm[6] * px + cm[7] * py + cm[8] * pz + t2;
    bool m = z > NEARZ;
    const float zs = m ? z : 1.0f;
    const float u = x / zs;
    const float v = y / zs;
    m = m && (fabsf(u) < LIMU) && (fabsf(v) < LIMV);
    const float iz = 1.0f / zs;
    const float iz2 = iz * iz;

    float Rg[9];
    quat_to_rot(quat[4 * i], quat[4 * i + 1], quat[4 * i + 2], quat[4 * i + 3],
                Rg);
    const float s0 = scale[3 * i], s1 = scale[3 * i + 1], s2 = scale[3 * i + 2];
    const float RS0 = Rg[0] * s0, RS1 = Rg[1] * s1, RS2 = Rg[2] * s2;
    const float RS3 = Rg[3] * s0, RS4 = Rg[4] * s1, RS5 = Rg[5] * s2;
    const float RS6 = Rg[6] * s0, RS7 = Rg[7] * s1, RS8 = Rg[8] * s2;

    const float xiz2 = x * iz2, yiz2 = y * iz2;
    const float w00 = iz * cm[0] - xiz2 * cm[6];
    const float w01 = iz * cm[1] - xiz2 * cm[7];
    const float w02 = iz * cm[2] - xiz2 * cm[8];
    const float w10 = iz * cm[3] - yiz2 * cm[6];
    const float w11 = iz * cm[4] - yiz2 * cm[7];
    const float w12 = iz * cm[5] - yiz2 * cm[8];

    const float e00 = w00 * RS0 + w01 * RS3 + w02 * RS6;
    const float e01 = w00 * RS1 + w01 * RS4 + w02 * RS7;
    const float e02 = w00 * RS2 + w01 * RS5 + w02 * RS8;
    const float e10 = w10 * RS0 + w11 * RS3 + w12 * RS6;
    const float e11 = w10 * RS1 + w11 * RS4 + w12 * RS7;
    const float e12 = w10 * RS2 + w11 * RS5 + w12 * RS8;

    const float a = e00 * e00 + e01 * e01 + e02 * e02 + EPS_C;
    const float b = e00 * e10 + e01 * e11 + e02 * e12;
    const float c = e10 * e10 + e11 * e11 + e12 * e12 + EPS_C;
    const float invdet = 1.0f / fmaxf(a * c - b * b, 1e-12f);
    // prescaled log2-domain conic: pw = A2*dx^2 + B2*dx*dy + C2*dy^2
    const float A2 = -0.5f * LOG2E * (c * invdet);
    const float C2 = -0.5f * LOG2E * (a * invdet);
    const float B2 = LOG2E * (b * invdet);

    // conservative bbox half-extents of the pw = -L2CUT level set
    // max|dx| on level set: dx^2 = -L / (A2 - B2^2/(4*C2))  (denominator < 0)
    float dxm, dym;
    if (m) {
        const float dA = fminf(A2 - (B2 * B2) / (4.0f * C2), -1e-30f);
        const float dC = fminf(C2 - (B2 * B2) / (4.0f * A2), -1e-30f);
        dxm = sqrtf(-L2CUT / dA);
        dym = sqrtf(-L2CUT / dC);
    } else {
        dxm = -1e30f;  // overlap test always fails -> binned nowhere
        dym = -1e30f;
    }

    // rank = # keys < mine (keys unique -> exact stable argsort), 2 keys/b128
    const unsigned long long myk = skey[i];
    const ulonglong2* sk2 = (const ulonglong2*)skey;
    int rank = 0;
#pragma unroll 8
    for (int j2 = 0; j2 < NG / 2; ++j2) {
        const ulonglong2 kk = sk2[j2];
        rank += (kk.x < myk) ? 1 : 0;
        rank += (kk.y < myk) ? 1 : 0;
    }

    float4* dst = (float4*)(rec + rank * GSTRIDE);
    dst[0] = make_float4(u, v, A2, B2);
    dst[1] = make_float4(C2, m ? opa[i] : 0.0f, rgb[3 * i], rgb[3 * i + 1]);
    dst[2] = make_float4(rgb[3 * i + 2], dxm, dym, 0.0f);
}

// 64 blocks (one per 16x16 tile) x 256 threads (one per pixel).
// Phase 1: scan all sorted records, bbox-test vs tile, build ORDERED local
//          list via ballot+prefix (depth order preserved).
// Phase 2: stage hit records into LDS in chunks, composite sequentially.
// Exact compositing order -> no partials, no combine kernel, no fences.
__global__ __launch_bounds__(256) void render_tiled_kernel(
    const float* __restrict__ rec, float* __restrict__ out) {
    __shared__ int list[NG];            // 8 KB
    __shared__ float buf[CHUNK * GSTRIDE];  // 12 KB
    __shared__ int wcnt[4];

    const int tid = threadIdx.x;
    const int lane = tid & 63;
    const int w = tid >> 6;
    const int tx = blockIdx.x & 7;
    const int ty = blockIdx.x >> 3;

    // tile bounds in camera-plane coords (pixel centers only)
    const float ulo = (tx * TILE + 0.5f - IMG_W * 0.5f) / F_FX;
    const float uhi = (tx * TILE + TILE - 0.5f - IMG_W * 0.5f) / F_FX;
    const float vlo = (ty * TILE + 0.5f - IMG_H * 0.5f) / F_FY;
    const float vhi = (ty * TILE + TILE - 0.5f - IMG_H * 0.5f) / F_FY;

    // phase 1: ordered compaction of overlapping records
    int base = 0;
#pragma unroll
    for (int c = 0; c < NG / 256; ++c) {
        const int idx = c * 256 + tid;
        const float4 f0 = *(const float4*)(rec + idx * GSTRIDE);      // u v A2 B2
        const float4 f2 = *(const float4*)(rec + idx * GSTRIDE + 8);  // b dxm dym _
        const bool hit = (f0.x + f2.y >= ulo) && (f0.x - f2.y <= uhi) &&
                         (f0.y + f2.z >= vlo) && (f0.y - f2.z <= vhi);
        const unsigned long long bal = __ballot(hit);
        if (lane == 0) wcnt[w] = __popcll(bal);
        __syncthreads();
        int off = base + __popcll(bal & ((1ULL << lane) - 1ULL));
#pragma unroll
        for (int ww = 0; ww < 4; ++ww) {
            if (ww < w) off += wcnt[ww];
            base += wcnt[ww];
        }
        if (hit) list[off] = idx;
        __syncthreads();  // protect wcnt for next chunk / list before reads
    }
    const int count = base;

    // this thread's pixel
    const int lx = tid & (TILE - 1);
    const int ly = tid / TILE;
    const int ix = tx * TILE + lx;
    const int iy = ty * TILE + ly;
    const float pu = (ix + 0.5f - IMG_W * 0.5f) / F_FX;
    const float pv = (iy + 0.5f - IMG_H * 0.5f) / F_FY;

    // phase 2: chunked stage + composite (depth order)
    float T = 1.0f, cr = 0.0f, cg = 0.0f, cb = 0.0f;
    for (int cb0 = 0; cb0 < count; cb0 += CHUNK) {
        const int n = min(CHUNK, count - cb0);
        for (int k = tid; k < n; k += 256) {
            const float4* g = (const float4*)(rec + list[cb0 + k] * GSTRIDE);
            float4* d = (float4*)(buf + k * GSTRIDE);
            d[0] = g[0];
            d[1] = g[1];
            d[2] = g[2];
        }
        __syncthreads();
        for (int j = 0; j < n; ++j) {
            const float4 q0 = ((const float4*)buf)[j * 3];      // u v A2 B2
            const float4 q1 = ((const float4*)buf)[j * 3 + 1];  // C2 o r g
            const float qb = buf[j * GSTRIDE + 8];              // b
            const float dx = pu - q0.x;
            const float dy = pv - q0.y;
            const float pwa = fmaf(q0.z, dx, q0.w * dy);  // A2*dx + B2*dy
            float pw = fmaf(dx, pwa, q1.x * dy * dy);     // + C2*dy^2
            pw = fminf(pw, 0.0f);
            const float al = fminf(q1.y * __builtin_amdgcn_exp2f(pw), 0.99f);
            const float wgt = T * al;
            cr = fmaf(wgt, q1.z, cr);
            cg = fmaf(wgt, q1.w, cg);
            cb = fmaf(wgt, qb, cb);
            T -= wgt;  // == T*(1-al)
        }
        __syncthreads();  // protect buf for next chunk
    }

    const int p = iy * IMG_W + ix;
    out[3 * p + 0] = cr;
    out[3 * p + 1] = cg;
    out[3 * p + 2] = cb;
}

extern "C" void kernel_launch(void* const* d_in, const int* in_sizes, int n_in,
                              void* d_out, int out_size, void* d_ws,
                              size_t ws_size, hipStream_t stream) {
    const float* pos   = (const float*)d_in[0];
    const float* rgb   = (const float*)d_in[1];
    const float* opa   = (const float*)d_in[2];
    const float* quat  = (const float*)d_in[3];
    const float* scale = (const float*)d_in[4];
    const float* wq    = (const float*)d_in[5];
    const float* wt    = (const float*)d_in[6];
    float* rec = (float*)d_ws;
    float* out = (float*)d_out;

    prep_rank_kernel<<<NG / 256, 256, 0, stream>>>(pos, rgb, opa, quat, scale,
                                                   wq, wt, rec);
    render_tiled_kernel<<<64, 256, 0, stream>>>(rec, out);
}

// Round 6
// 95.538 us; speedup vs baseline: 1.9822x; 1.1194x over previous
//
#include <hip/hip_runtime.h>
#include <math.h>

#define NG    2048
#define IMG_W 128
#define IMG_H 128
#define TILE  16               // 16x16 px tiles, 8x8 = 64 tiles
#define MAXH  512              // hit cap per tile (mean ~70, 50-sigma margin)
#define F_FX  100.0f
#define F_FY  100.0f
#define NEARZ 1.1f
#define EPS_C 1e-6f
#define LIMU  (IMG_W / (2.0f * F_FX))
#define LIMV  (IMG_H / (2.0f * F_FY))
#define LOG2E 1.4426950408889634f
#define L2CUT 30.0f            // log2 alpha cutoff: culled pairs < opa*2^-30

// Single dispatch, 64 blocks (one per tile), 256 threads (one per pixel).
// Each block redundantly preps all 2048 gaussians (projection+conic+bbox,
// ~1us — cheaper than a separate kernel + dispatch gap + global round-trip),
// ballot-compacts tile hits into LDS, rank-orders them by globally-consistent
// depth keys (exact reference permutation restricted to the hit set), and
// composites front-to-back. Zero cross-block traffic, zero fences (R3 lesson:
// device-scope fences cost ~90us on gfx950), zero workspace usage.

__device__ __forceinline__ void quat_to_rot(float w, float x, float y, float z,
                                            float R[9]) {
    float n = sqrtf(w * w + x * x + y * y + z * z) + 1e-12f;
    w /= n; x /= n; y /= n; z /= n;
    R[0] = 1.0f - 2.0f * (y * y + z * z);
    R[1] = 2.0f * (x * y - w * z);
    R[2] = 2.0f * (x * z + w * y);
    R[3] = 2.0f * (x * y + w * z);
    R[4] = 1.0f - 2.0f * (x * x + z * z);
    R[5] = 2.0f * (y * z - w * x);
    R[6] = 2.0f * (x * z - w * y);
    R[7] = 2.0f * (y * z + w * x);
    R[8] = 1.0f - 2.0f * (x * x + y * y);
}

__global__ __launch_bounds__(256) void splat_fused_kernel(
    const float* __restrict__ pos, const float* __restrict__ rgb,
    const float* __restrict__ opa, const float* __restrict__ quat,
    const float* __restrict__ scale, const float* __restrict__ wq,
    const float* __restrict__ wt, float* __restrict__ out) {
    __shared__ __align__(16) float srec[MAXH * 12];       // 24 KB
    __shared__ __align__(16) unsigned long long skey[MAXH]; // 4 KB
    __shared__ unsigned short ord[MAXH];                  // 1 KB
    __shared__ int wcnt[4];

    const int tid = threadIdx.x;
    const int lane = tid & 63;
    const int w = tid >> 6;
    const int tx = blockIdx.x & 7;
    const int ty = blockIdx.x >> 3;

    // camera rotation (uniform, cheap)
    float cm[9];
    quat_to_rot(wq[0], wq[1], wq[2], wq[3], cm);
    const float t0 = wt[0], t1 = wt[1], t2 = wt[2];

    // tile bounds in camera-plane coords (pixel centers)
    const float ulo = (tx * TILE + 0.5f - IMG_W * 0.5f) / F_FX;
    const float uhi = (tx * TILE + TILE - 0.5f - IMG_W * 0.5f) / F_FX;
    const float vlo = (ty * TILE + 0.5f - IMG_H * 0.5f) / F_FY;
    const float vhi = (ty * TILE + TILE - 0.5f - IMG_H * 0.5f) / F_FY;

    // ---- phase 1: prep all gaussians, compact tile hits into LDS ----
    int base = 0;
#pragma unroll
    for (int k = 0; k < NG / 256; ++k) {
        const int g = k * 256 + tid;
        const float px = pos[3 * g], py = pos[3 * g + 1], pz = pos[3 * g + 2];
        const float x = cm[0] * px + cm[1] * py + cm[2] * pz + t0;
        const float y = cm[3] * px + cm[4] * py + cm[5] * pz + t1;
        const float z = cm[6] * px + cm[7] * py + cm[8] * pz + t2;
        const float dn = sqrtf(x * x + y * y + z * z);
        bool m = z > NEARZ;
        const float zs = m ? z : 1.0f;
        const float u = x / zs;
        const float v = y / zs;
        m = m && (fabsf(u) < LIMU) && (fabsf(v) < LIMV);
        const float iz = 1.0f / zs;
        const float iz2 = iz * iz;

        const float4 q4 = *(const float4*)(quat + 4 * g);
        float Rg[9];
        quat_to_rot(q4.x, q4.y, q4.z, q4.w, Rg);
        const float s0 = scale[3 * g], s1 = scale[3 * g + 1],
                    s2 = scale[3 * g + 2];
        const float RS0 = Rg[0] * s0, RS1 = Rg[1] * s1, RS2 = Rg[2] * s2;
        const float RS3 = Rg[3] * s0, RS4 = Rg[4] * s1, RS5 = Rg[5] * s2;
        const float RS6 = Rg[6] * s0, RS7 = Rg[7] * s1, RS8 = Rg[8] * s2;

        const float xiz2 = x * iz2, yiz2 = y * iz2;
        const float w00 = iz * cm[0] - xiz2 * cm[6];
        const float w01 = iz * cm[1] - xiz2 * cm[7];
        const float w02 = iz * cm[2] - xiz2 * cm[8];
        const float w10 = iz * cm[3] - yiz2 * cm[6];
        const float w11 = iz * cm[4] - yiz2 * cm[7];
        const float w12 = iz * cm[5] - yiz2 * cm[8];

        const float e00 = w00 * RS0 + w01 * RS3 + w02 * RS6;
        const float e01 = w00 * RS1 + w01 * RS4 + w02 * RS7;
        const float e02 = w00 * RS2 + w01 * RS5 + w02 * RS8;
        const float e10 = w10 * RS0 + w11 * RS3 + w12 * RS6;
        const float e11 = w10 * RS1 + w11 * RS4 + w12 * RS7;
        const float e12 = w10 * RS2 + w11 * RS5 + w12 * RS8;

        const float a = e00 * e00 + e01 * e01 + e02 * e02 + EPS_C;
        const float b = e00 * e10 + e01 * e11 + e02 * e12;
        const float c = e10 * e10 + e11 * e11 + e12 * e12 + EPS_C;
        const float invdet = 1.0f / fmaxf(a * c - b * b, 1e-12f);
        // prescaled log2-domain conic: pw = A2*dx^2 + B2*dx*dy + C2*dy^2
        const float A2 = -0.5f * LOG2E * (c * invdet);
        const float C2 = -0.5f * LOG2E * (a * invdet);
        const float B2 = LOG2E * (b * invdet);

        // conservative bbox half-extents of the pw = -L2CUT level set
        bool hit = false;
        if (m) {
            const float dA = fminf(A2 - (B2 * B2) / (4.0f * C2), -1e-30f);
            const float dC = fminf(C2 - (B2 * B2) / (4.0f * A2), -1e-30f);
            const float dxm = sqrtf(-L2CUT / dA);
            const float dym = sqrtf(-L2CUT / dC);
            hit = (u + dxm >= ulo) && (u - dxm <= uhi) && (v + dym >= vlo) &&
                  (v - dym <= vhi);
        }

        const unsigned long long bal = __ballot(hit);
        if (lane == 0) wcnt[w] = __popcll(bal);
        __syncthreads();
        int off = base + __popcll(bal & ((1ULL << lane) - 1ULL));
#pragma unroll
        for (int ww = 0; ww < 4; ++ww) {
            if (ww < w) off += wcnt[ww];
            base += wcnt[ww];
        }
        if (hit && off < MAXH) {
            skey[off] = (((unsigned long long)__float_as_uint(dn)) << 32) |
                        (unsigned long long)(unsigned)g;
            float4* d = (float4*)(srec + off * 12);
            d[0] = make_float4(u, v, A2, B2);
            d[1] = make_float4(C2, opa[g], rgb[3 * g], rgb[3 * g + 1]);
            d[2] = make_float4(rgb[3 * g + 2], 0.0f, 0.0f, 0.0f);
        }
        __syncthreads();  // protect wcnt/skey for next chunk
    }
    const int cnt = min(base, MAXH);

    // ---- phase 2: rank-order hits (keys globally consistent & unique) ----
    for (int h = tid; h < cnt; h += 256) {
        const unsigned long long myk = skey[h];
        int rank = 0;
        for (int j = 0; j < cnt; ++j) rank += (skey[j] < myk) ? 1 : 0;
        ord[rank] = (unsigned short)h;
    }
    __syncthreads();

    // ---- phase 3: composite front-to-back ----
    const int lx = tid & (TILE - 1);
    const int ly = tid / TILE;
    const int ix = tx * TILE + lx;
    const int iy = ty * TILE + ly;
    const float pu = (ix + 0.5f - IMG_W * 0.5f) / F_FX;
    const float pv = (iy + 0.5f - IMG_H * 0.5f) / F_FY;

    float T = 1.0f, cr = 0.0f, cg = 0.0f, cb = 0.0f;
    for (int j = 0; j < cnt; ++j) {
        const int h = ord[j];
        const float4 q0 = ((const float4*)srec)[h * 3];      // u v A2 B2
        const float4 q1 = ((const float4*)srec)[h * 3 + 1];  // C2 o r g
        const float qb = srec[h * 12 + 8];                   // b
        const float dx = pu - q0.x;
        const float dy = pv - q0.y;
        const float pwa = fmaf(q0.z, dx, q0.w * dy);  // A2*dx + B2*dy
        float pw = fmaf(dx, pwa, q1.x * dy * dy);     // + C2*dy^2
        pw = fminf(pw, 0.0f);
        const float al = fminf(q1.y * __builtin_amdgcn_exp2f(pw), 0.99f);
        const float wgt = T * al;
        cr = fmaf(wgt, q1.z, cr);
        cg = fmaf(wgt, q1.w, cg);
        cb = fmaf(wgt, qb, cb);
        T -= wgt;  // == T*(1-al)
    }

    const int p = iy * IMG_W + ix;
    out[3 * p + 0] = cr;
    out[3 * p + 1] = cg;
    out[3 * p + 2] = cb;
}

extern "C" void kernel_launch(void* const* d_in, const int* in_sizes, int n_in,
                              void* d_out, int out_size, void* d_ws,
                              size_t ws_size, hipStream_t stream) {
    const float* pos   = (const float*)d_in[0];
    const float* rgb   = (const float*)d_in[1];
    const float* opa   = (const float*)d_in[2];
    const float* quat  = (const float*)d_in[3];
    const float* scale = (const float*)d_in[4];
    const float* wq    = (const float*)d_in[5];
    const float* wt    = (const float*)d_in[6];
    float* out = (float*)d_out;

    splat_fused_kernel<<<64, 256, 0, stream>>>(pos, rgb, opa, quat, scale, wq,
                                               wt, out);
}